// Round 1
// baseline (615.010 us; speedup 1.0000x reference)
//
#include <hip/hip_runtime.h>
#include <stdint.h>

// ---------------------------------------------------------------------------
// SelfAttention2d: B=4, C=256, H=W=64 (N=4096), NUM_HEADS=4 (hd=64), GROUPS=8
// Pipeline: groupnorm -> qkv 1x1 -> attention -> proj 1x1 -> +x
// All matmuls in bf16 MFMA (16x16x32), fp32 accumulate.
// ---------------------------------------------------------------------------

#define B_  4
#define C_  256
#define N_  4096
#define NH_ 4
#define HD_ 64
#define G_  8
#define CPG_ 32           // channels per group
#define GRP_ELEMS (CPG_ * N_)   // 131072

typedef __attribute__((ext_vector_type(8))) short short8;
typedef __attribute__((ext_vector_type(4))) float f32x4;
typedef __attribute__((ext_vector_type(4))) unsigned short us4;

__device__ __forceinline__ unsigned short f2bf(float f) {
  union { float f; unsigned u; } v; v.f = f;
  unsigned r = v.u + 0x7FFFu + ((v.u >> 16) & 1u);
  return (unsigned short)(r >> 16);
}

// ---------------------------------------------------------------------------
// Kernel 1: convert qkv_w (768x256) and proj_w (256x256) fp32 -> bf16
// ---------------------------------------------------------------------------
__global__ void cvt_weights(const float* __restrict__ qkvw,
                            const float* __restrict__ projw,
                            unsigned short* __restrict__ wq,
                            unsigned short* __restrict__ wp) {
  int i = blockIdx.x * 256 + threadIdx.x;
  if (i < 768 * 256) wq[i] = f2bf(qkvw[i]);
  if (i < 256 * 256) wp[i] = f2bf(projw[i]);
}

// ---------------------------------------------------------------------------
// Kernel 2: groupnorm partial sums. 512 blocks = (b,g,slice16), 256 threads.
// Each block reduces 32c x 256n.
// ---------------------------------------------------------------------------
__global__ void gn_partial(const float* __restrict__ x, float* __restrict__ partial) {
  int idx = blockIdx.x;
  int slice = idx & 15, g = (idx >> 4) & 7, b = idx >> 7;
  int t = threadIdx.x;
  const float* base = x + (size_t)(b * C_ + g * CPG_) * N_ + slice * 256;
  float s = 0.f, sq = 0.f;
#pragma unroll
  for (int cc = 0; cc < CPG_; cc++) {
    float v = base[(size_t)cc * N_ + t];
    s += v; sq += v * v;
  }
#pragma unroll
  for (int off = 32; off; off >>= 1) {
    s  += __shfl_down(s,  off, 64);
    sq += __shfl_down(sq, off, 64);
  }
  __shared__ float ls[8];
  int wave = t >> 6, lane = t & 63;
  if (lane == 0) { ls[wave * 2] = s; ls[wave * 2 + 1] = sq; }
  __syncthreads();
  if (t == 0) {
    float S = ls[0] + ls[2] + ls[4] + ls[6];
    float SQ = ls[1] + ls[3] + ls[5] + ls[7];
    partial[idx * 2] = S; partial[idx * 2 + 1] = SQ;
  }
}

// ---------------------------------------------------------------------------
// Kernel 3: finalize stats. 32 groups, stats[g] = {mean, rstd}
// ---------------------------------------------------------------------------
__global__ void gn_finalize(const float* __restrict__ partial, float* __restrict__ stats) {
  int t = threadIdx.x;
  if (t < 32) {
    float s = 0.f, sq = 0.f;
    for (int i = 0; i < 16; i++) {
      s  += partial[(t * 16 + i) * 2];
      sq += partial[(t * 16 + i) * 2 + 1];
    }
    const float inv = 1.0f / (float)GRP_ELEMS;
    float mean = s * inv;
    float var = sq * inv - mean * mean;
    stats[t * 2] = mean;
    stats[t * 2 + 1] = rsqrtf(var + 1e-5f);
  }
}

// ---------------------------------------------------------------------------
// Kernel 4: normalize + transpose. x (B,C,N) fp32 -> hT (B,N,C) bf16.
// grid (64 nt, 8 ctile, 4 b), 256 threads; 32c x 64n tile via LDS.
// ---------------------------------------------------------------------------
__global__ void gn_apply(const float* __restrict__ x,
                         const float* __restrict__ nw, const float* __restrict__ nb,
                         const float* __restrict__ stats, unsigned short* __restrict__ hT) {
  int nt = blockIdx.x, ct = blockIdx.y, b = blockIdx.z;
  __shared__ unsigned short tile[32][72];
  int t = threadIdx.x;
  int n_loc = t & 63, c_loc = t >> 6;  // c_loc 0..3
  float mean = stats[(b * G_ + ct) * 2];
  float rstd = stats[(b * G_ + ct) * 2 + 1];
  const float* xb = x + (size_t)(b * C_ + ct * CPG_) * N_ + nt * 64;
#pragma unroll
  for (int rr = 0; rr < 8; rr++) {
    int cc = rr * 4 + c_loc;
    int c = ct * CPG_ + cc;
    float v = xb[(size_t)cc * N_ + n_loc];
    v = (v - mean) * rstd * nw[c] + nb[c];
    tile[cc][n_loc] = f2bf(v);
  }
  __syncthreads();
  int c2 = t & 31, n2 = t >> 5;  // n2 0..7
  unsigned short* out = hT + ((size_t)(b * N_ + nt * 64)) * C_ + ct * CPG_ + c2;
#pragma unroll
  for (int pass = 0; pass < 8; pass++) {
    int n = pass * 8 + n2;
    out[(size_t)n * C_] = tile[c2][n];
  }
}

// ---------------------------------------------------------------------------
// Kernel 5: qkv GEMM. D[o][n] = sum_c Wqkv[o][c] * hT[n][c] + bias.
// grid (64 nt, 12 ot, 4 b), 256 threads (4 waves, wave = 16 o-rows).
// Epilogue: o<256 -> Qt (bh,n,c) *0.125*log2e; o<512 -> Kt (bh,n,c);
//           else  -> V (bh,c,n).
// ---------------------------------------------------------------------------
__global__ __launch_bounds__(256) void qkv_gemm(
    const unsigned short* __restrict__ hT, const unsigned short* __restrict__ wq,
    const float* __restrict__ qb,
    unsigned short* __restrict__ Qt, unsigned short* __restrict__ Kt,
    unsigned short* __restrict__ V) {
  int nt = blockIdx.x, ot = blockIdx.y, b = blockIdx.z;
  int t = threadIdx.x;
  int wave = t >> 6, lane = t & 63, l15 = lane & 15, quad = lane >> 4;
  int o_base = ot * 64 + wave * 16;

  f32x4 acc[4];
#pragma unroll
  for (int tt = 0; tt < 4; tt++) acc[tt] = (f32x4){0.f, 0.f, 0.f, 0.f};

  const short8* arow = reinterpret_cast<const short8*>(wq + (size_t)(o_base + l15) * C_);
  const short8* brow[4];
#pragma unroll
  for (int tt = 0; tt < 4; tt++)
    brow[tt] = reinterpret_cast<const short8*>(
        hT + ((size_t)(b * N_ + nt * 64 + tt * 16 + l15)) * C_);

#pragma unroll
  for (int kk = 0; kk < 8; kk++) {
    short8 a = arow[kk * 4 + quad];
#pragma unroll
    for (int tt = 0; tt < 4; tt++) {
      short8 bf = brow[tt][kk * 4 + quad];
      acc[tt] = __builtin_amdgcn_mfma_f32_16x16x32_bf16(a, bf, acc[tt], 0, 0, 0);
    }
  }

  int sec = ot >> 2, head = ot & 3;
  int cw = wave * 16 + quad * 4;      // within-head channel base for this lane
  int bh = b * NH_ + head;
  const float SC = 0.125f * 1.44269504088896340736f;  // 1/sqrt(hd) * log2(e)

  if (sec == 0) {
#pragma unroll
    for (int tt = 0; tt < 4; tt++) {
      int n = nt * 64 + tt * 16 + l15;
      us4 pk;
#pragma unroll
      for (int i = 0; i < 4; i++)
        pk[i] = f2bf((acc[tt][i] + qb[ot * 64 + cw + i]) * SC);
      *reinterpret_cast<us4*>(Qt + ((size_t)bh * N_ + n) * HD_ + cw) = pk;
    }
  } else if (sec == 1) {
#pragma unroll
    for (int tt = 0; tt < 4; tt++) {
      int n = nt * 64 + tt * 16 + l15;
      us4 pk;
#pragma unroll
      for (int i = 0; i < 4; i++)
        pk[i] = f2bf(acc[tt][i] + qb[ot * 64 + cw + i]);
      *reinterpret_cast<us4*>(Kt + ((size_t)bh * N_ + n) * HD_ + cw) = pk;
    }
  } else {
#pragma unroll
    for (int tt = 0; tt < 4; tt++) {
      int n = nt * 64 + tt * 16 + l15;
#pragma unroll
      for (int i = 0; i < 4; i++)
        V[((size_t)bh * HD_ + cw + i) * N_ + n] = f2bf(acc[tt][i] + qb[ot * 64 + cw + i]);
    }
  }
}

// ---------------------------------------------------------------------------
// Kernel 6: flash attention. grid (64 qt, 16 bh), 256 threads (4 waves x 16 q).
// Q pre-scaled by 0.125*log2e so softmax runs in exp2 domain.
// Out: aoT (B, N, C) bf16.
// ---------------------------------------------------------------------------
__global__ __launch_bounds__(256) void flash_attn(
    const unsigned short* __restrict__ Qt, const unsigned short* __restrict__ Kt,
    const unsigned short* __restrict__ Vv, unsigned short* __restrict__ aoT) {
  int qt = blockIdx.x, bh = blockIdx.y;
  int b = bh >> 2, head = bh & 3;
  int t = threadIdx.x;
  int wave = t >> 6, lane = t & 63, l15 = lane & 15, quad = lane >> 4;
  const unsigned short* Qb = Qt + (size_t)bh * N_ * HD_;
  const unsigned short* Kb = Kt + (size_t)bh * N_ * HD_;
  const unsigned short* Vb = Vv + (size_t)bh * HD_ * N_;
  int q_base = qt * 64 + wave * 16;

  short8 qf0 = *reinterpret_cast<const short8*>(Qb + (size_t)(q_base + l15) * HD_ + quad * 8);
  short8 qf1 = *reinterpret_cast<const short8*>(Qb + (size_t)(q_base + l15) * HD_ + 32 + quad * 8);

  __shared__ __align__(16) unsigned short Ps[4][16][72];

  f32x4 oa[4];
#pragma unroll
  for (int ct = 0; ct < 4; ct++) oa[ct] = (f32x4){0.f, 0.f, 0.f, 0.f};
  float m_i[4], l_i[4];
#pragma unroll
  for (int i = 0; i < 4; i++) { m_i[i] = -INFINITY; l_i[i] = 0.f; }

  for (int kt = 0; kt < 64; kt++) {
    int m0 = kt * 64;
    // ---- S = Q^T K over this key tile (16q x 64keys per wave) ----
    f32x4 s[4];
#pragma unroll
    for (int tt = 0; tt < 4; tt++) {
      short8 k0 = *reinterpret_cast<const short8*>(Kb + (size_t)(m0 + tt * 16 + l15) * HD_ + quad * 8);
      short8 k1 = *reinterpret_cast<const short8*>(Kb + (size_t)(m0 + tt * 16 + l15) * HD_ + 32 + quad * 8);
      f32x4 z = (f32x4){0.f, 0.f, 0.f, 0.f};
      z = __builtin_amdgcn_mfma_f32_16x16x32_bf16(qf0, k0, z, 0, 0, 0);
      s[tt] = __builtin_amdgcn_mfma_f32_16x16x32_bf16(qf1, k1, z, 0, 0, 0);
    }
    // ---- V tile b-frags ----
    short8 vf[4][2];
#pragma unroll
    for (int ct = 0; ct < 4; ct++)
#pragma unroll
      for (int kk = 0; kk < 2; kk++)
        vf[ct][kk] = *reinterpret_cast<const short8*>(
            Vb + (size_t)(ct * 16 + l15) * N_ + m0 + kk * 32 + quad * 8);
    // ---- online softmax (rows quad*4+i, cols across 16 lanes x 4 subtiles) ----
    float p[4][4];
#pragma unroll
    for (int i = 0; i < 4; i++) {
      float rm = fmaxf(fmaxf(s[0][i], s[1][i]), fmaxf(s[2][i], s[3][i]));
#pragma unroll
      for (int off = 1; off < 16; off <<= 1) rm = fmaxf(rm, __shfl_xor(rm, off, 64));
      float mn = fmaxf(m_i[i], rm);
      float al = exp2f(m_i[i] - mn);
      float rs = 0.f;
#pragma unroll
      for (int tt = 0; tt < 4; tt++) { p[tt][i] = exp2f(s[tt][i] - mn); rs += p[tt][i]; }
#pragma unroll
      for (int off = 1; off < 16; off <<= 1) rs += __shfl_xor(rs, off, 64);
      l_i[i] = l_i[i] * al + rs;
      m_i[i] = mn;
#pragma unroll
      for (int ct = 0; ct < 4; ct++) oa[ct][i] *= al;
    }
    // ---- P: C-layout -> A-layout via wave-private LDS ----
#pragma unroll
    for (int tt = 0; tt < 4; tt++)
#pragma unroll
      for (int i = 0; i < 4; i++)
        Ps[wave][quad * 4 + i][tt * 16 + l15] = f2bf(p[tt][i]);
    short8 pf0 = *reinterpret_cast<const short8*>(&Ps[wave][l15][quad * 8]);
    short8 pf1 = *reinterpret_cast<const short8*>(&Ps[wave][l15][32 + quad * 8]);
    // ---- O += P V^T ----
#pragma unroll
    for (int ct = 0; ct < 4; ct++) {
      oa[ct] = __builtin_amdgcn_mfma_f32_16x16x32_bf16(pf0, vf[ct][0], oa[ct], 0, 0, 0);
      oa[ct] = __builtin_amdgcn_mfma_f32_16x16x32_bf16(pf1, vf[ct][1], oa[ct], 0, 0, 0);
    }
  }
#pragma unroll
  for (int i = 0; i < 4; i++) l_i[i] = 1.0f / l_i[i];
#pragma unroll
  for (int ct = 0; ct < 4; ct++)
#pragma unroll
    for (int i = 0; i < 4; i++) {
      int n = q_base + quad * 4 + i;
      aoT[((size_t)(b * N_ + n)) * C_ + head * HD_ + ct * 16 + l15] = f2bf(oa[ct][i] * l_i[i]);
    }
}

// ---------------------------------------------------------------------------
// Kernel 7: proj GEMM + bias + residual. out[b][o][n] fp32.
// grid (64 nt, 4 ot, 4 b), 256 threads.
// ---------------------------------------------------------------------------
__global__ __launch_bounds__(256) void proj_gemm(
    const unsigned short* __restrict__ aoT, const unsigned short* __restrict__ wp,
    const float* __restrict__ pb, const float* __restrict__ x,
    float* __restrict__ out) {
  int nt = blockIdx.x, ot = blockIdx.y, b = blockIdx.z;
  int t = threadIdx.x;
  int wave = t >> 6, lane = t & 63, l15 = lane & 15, quad = lane >> 4;
  int o_base = ot * 64 + wave * 16;

  f32x4 acc[4];
#pragma unroll
  for (int tt = 0; tt < 4; tt++) acc[tt] = (f32x4){0.f, 0.f, 0.f, 0.f};

  const short8* arow = reinterpret_cast<const short8*>(wp + (size_t)(o_base + l15) * C_);
  const short8* brow[4];
#pragma unroll
  for (int tt = 0; tt < 4; tt++)
    brow[tt] = reinterpret_cast<const short8*>(
        aoT + ((size_t)(b * N_ + nt * 64 + tt * 16 + l15)) * C_);

#pragma unroll
  for (int kk = 0; kk < 8; kk++) {
    short8 a = arow[kk * 4 + quad];
#pragma unroll
    for (int tt = 0; tt < 4; tt++) {
      short8 bf = brow[tt][kk * 4 + quad];
      acc[tt] = __builtin_amdgcn_mfma_f32_16x16x32_bf16(a, bf, acc[tt], 0, 0, 0);
    }
  }
#pragma unroll
  for (int tt = 0; tt < 4; tt++) {
    int n = nt * 64 + tt * 16 + l15;
#pragma unroll
    for (int i = 0; i < 4; i++) {
      int o = o_base + quad * 4 + i;
      size_t idx = ((size_t)(b * C_ + o)) * N_ + n;
      out[idx] = acc[tt][i] + pb[o] + x[idx];
    }
  }
}

// ---------------------------------------------------------------------------
extern "C" void kernel_launch(void* const* d_in, const int* in_sizes, int n_in,
                              void* d_out, int out_size, void* d_ws, size_t ws_size,
                              hipStream_t stream) {
  const float* x      = (const float*)d_in[0];
  const float* norm_w = (const float*)d_in[1];
  const float* norm_b = (const float*)d_in[2];
  const float* qkv_w  = (const float*)d_in[3];
  const float* qkv_b  = (const float*)d_in[4];
  const float* proj_w = (const float*)d_in[5];
  const float* proj_b = (const float*)d_in[6];
  float* out = (float*)d_out;

  char* ws = (char*)d_ws;
  size_t off = 0;
  auto alloc = [&](size_t bytes) { size_t o = off; off = (off + bytes + 255) & ~(size_t)255; return o; };
  size_t off_partial = alloc(512 * 2 * sizeof(float));
  size_t off_stats   = alloc(32 * 2 * sizeof(float));
  size_t off_wq      = alloc((size_t)768 * 256 * 2);
  size_t off_wp      = alloc((size_t)256 * 256 * 2);
  size_t off_hT      = alloc((size_t)B_ * N_ * C_ * 2);
  size_t off_Qt      = alloc((size_t)B_ * NH_ * N_ * HD_ * 2);
  size_t off_Kt      = alloc((size_t)B_ * NH_ * N_ * HD_ * 2);
  size_t off_V       = alloc((size_t)B_ * NH_ * HD_ * N_ * 2);
  size_t off_aoT     = alloc((size_t)B_ * N_ * C_ * 2);

  float* partial = (float*)(ws + off_partial);
  float* stats   = (float*)(ws + off_stats);
  unsigned short* wq  = (unsigned short*)(ws + off_wq);
  unsigned short* wp  = (unsigned short*)(ws + off_wp);
  unsigned short* hT  = (unsigned short*)(ws + off_hT);
  unsigned short* Qt  = (unsigned short*)(ws + off_Qt);
  unsigned short* Kt  = (unsigned short*)(ws + off_Kt);
  unsigned short* V   = (unsigned short*)(ws + off_V);
  unsigned short* aoT = (unsigned short*)(ws + off_aoT);

  cvt_weights<<<768, 256, 0, stream>>>(qkv_w, proj_w, wq, wp);
  gn_partial<<<512, 256, 0, stream>>>(x, partial);
  gn_finalize<<<1, 64, 0, stream>>>(partial, stats);
  gn_apply<<<dim3(64, 8, 4), 256, 0, stream>>>(x, norm_w, norm_b, stats, hT);
  qkv_gemm<<<dim3(64, 12, 4), 256, 0, stream>>>(hT, wq, qkv_b, Qt, Kt, V);
  flash_attn<<<dim3(64, 16), 256, 0, stream>>>(Qt, Kt, V, aoT);
  proj_gemm<<<dim3(64, 4, 4), 256, 0, stream>>>(aoT, wp, proj_b, x, out);
}